// Round 2
// 303.239 us; speedup vs baseline: 1.0474x; 1.0474x over previous
//
#include <hip/hip_runtime.h>
#include <hip/hip_bf16.h>

#define B_ 4
#define N_ 2048
#define D_ 768
#define H_ 6
#define Do_ 128
#define M_ (B_*N_)      // 8192
#define C2_ (2*D_)      // 1536
#define SROW 49152      // B_*H_*N_

typedef __attribute__((ext_vector_type(8))) short bf16x8;
typedef __attribute__((ext_vector_type(4))) float f32x4;
typedef __attribute__((ext_vector_type(4))) int int4v;
typedef __attribute__((ext_vector_type(2))) int int2v;
typedef __attribute__((ext_vector_type(4))) float float4v;
typedef __attribute__((ext_vector_type(4))) unsigned short ushort4v;

__device__ __forceinline__ float b2f(short s){
    unsigned u = ((unsigned)(unsigned short)s) << 16;
    return __builtin_bit_cast(float, u);
}
__device__ __forceinline__ short f2b(float f){
    unsigned u = __builtin_bit_cast(unsigned, f);
    unsigned r = (u + 0x7fffu + ((u >> 16) & 1u)) >> 16;
    return (short)r;
}
// pack two f32 -> two bf16 (round-half-up) in one v_perm
__device__ __forceinline__ int pk2(float a, float b){
    unsigned ua = __builtin_bit_cast(unsigned, a) + 0x8000u;
    unsigned ub = __builtin_bit_cast(unsigned, b) + 0x8000u;
    return (int)__builtin_amdgcn_perm(ub, ua, 0x07060302u); // lo16=hi(ua), hi16=hi(ub)
}
__device__ __forceinline__ float fast_tanh(float x){
    float a = fabsf(x);
    float e = __expf(-2.0f * a);
    float t = (1.0f - e) / (1.0f + e);
    return copysignf(t, x);
}
// async global->LDS, 16B per lane. LDS dest = wave-uniform base + lane*16.
__device__ __forceinline__ void gload_lds16(const void* g, void* l){
    __builtin_amdgcn_global_load_lds((const __attribute__((address_space(1))) unsigned int*)g,
                                     (__attribute__((address_space(3))) unsigned int*)l,
                                     16, 0, 0);
}

// -------- Kernel A: pack B^T matrix (f32->bf16) + bit-pack adj (+ feat f32->bf16 if room) --------
__global__ __launch_bounds__(256) void k_prep_pack(const float* __restrict__ W,
                                                   const float* __restrict__ Hw,
                                                   const float* __restrict__ feat,
                                                   const int* __restrict__ adj,
                                                   short* __restrict__ bmat,
                                                   short* __restrict__ featbf,
                                                   unsigned char* __restrict__ pk){
    int bid = blockIdx.x, t = threadIdx.x;
    if (bid < C2_){
        int c = bid;
        if (c < D_){
            int hd = c >> 7, o = c & 127;
            const float* wp = W + hd*D_*Do_ + o;
            for (int k = t; k < D_; k += 256) bmat[c*D_ + k] = f2b(wp[k*Do_]);
        } else {
            int d = c - D_;
            const float* hp = Hw + d*D_;
            for (int k = t; k < D_; k += 256) bmat[c*D_ + k] = f2b(hp[k]);
        }
    } else if (bid < C2_ + 8192){
        int g = (bid - C2_)*256 + t;            // one byte per thread
        const int* ap = adj + (size_t)g*8;
        int4v a0 = *(const int4v*)ap;
        int4v a1 = *(const int4v*)(ap + 4);
        unsigned by = 0;
        #pragma unroll
        for (int i = 0; i < 4; i++){
            by |= (a0[i] ? 1u : 0u) << i;
            by |= (a1[i] ? 1u : 0u) << (i + 4);
        }
        pk[g] = (unsigned char)by;
    } else {
        int g = (bid - C2_ - 8192)*2048 + t*8;  // 8 f32 -> 8 bf16 per thread
        float4v a0 = *(const float4v*)&feat[g];
        float4v a1 = *(const float4v*)&feat[g + 4];
        int4v w;
        w[0] = pk2(a0[0], a0[1]); w[1] = pk2(a0[2], a0[3]);
        w[2] = pk2(a1[0], a1[1]); w[3] = pk2(a1[2], a1[3]);
        *(int4v*)&featbf[g] = w;
    }
}

// -------- Kernel B (primary): C[8192,1536] = Abf[8192,768] @ Bm^T, 128x128 tile --------
// m97 recipe: global_load_lds(16B) into unpadded [128][64] LDS, XOR-swizzled
// via per-lane global source (write side) + same XOR on ds_read (read side).
// XCD-chunked block remap: 96 consecutive tiles per XCD -> A-panels + B L2-resident.
__global__ __launch_bounds__(256) void k_gemm_bf(const short* __restrict__ Abf,
                                                 const short* __restrict__ Bm,
                                                 short* __restrict__ ht,
                                                 float* outg){
    __shared__ short As[128*64];    // 16KB, row = 64 bf16 = 128B, swizzled storage
    __shared__ short Bs[128*64];
    int lid = blockIdx.x;
    int nid = (lid & 7)*96 + (lid >> 3);        // bijective: 768 % 8 == 0
    int bx = nid % 12, by = nid / 12;           // col-tile (12), row-tile (64)
    int mBase = by * 128, cBase = bx * 128;
    int tid = threadIdx.x, wave = tid >> 6, lane = tid & 63, q = lane >> 4, nL = lane & 15;
    int wr = (wave >> 1) * 64, wc = (wave & 1) * 64;
    // staging: issue i covers rows [i*32, i*32+32); thread row = i*32 + tid/8,
    // source col-group XOR-swizzled so linear LDS write = swizzled layout.
    int srow = tid >> 3;                        // 0..31
    int sc16 = (tid & 7) ^ (srow & 7);
    const short* aSrc = Abf + (size_t)(mBase + srow)*D_ + sc16*8;
    const short* bSrc = Bm  + (size_t)(cBase + srow)*D_ + sc16*8;
    short* aDst = &As[wave*512];                // + i*2048 shorts (4KB/issue)
    short* bDst = &Bs[wave*512];
    f32x4 acc[4][4] = {};
    for (int kk = 0; kk < D_; kk += 64){
        __syncthreads();
        #pragma unroll
        for (int i = 0; i < 4; i++)
            gload_lds16(aSrc + (size_t)i*32*D_ + kk, aDst + i*2048);
        #pragma unroll
        for (int i = 0; i < 4; i++)
            gload_lds16(bSrc + (size_t)i*32*D_ + kk, bDst + i*2048);
        __syncthreads();                        // compiler drains vmcnt before barrier
        #pragma unroll
        for (int k2 = 0; k2 < 64; k2 += 32){
            bf16x8 aF[4], bF[4];
            int cb = (k2 >> 3) + q;             // pre-swizzle col16 (0..7)
            #pragma unroll
            for (int rt = 0; rt < 4; rt++){
                int r = wr + rt*16 + nL;
                aF[rt] = *(const bf16x8*)&As[r*64 + ((cb ^ (r & 7)) * 8)];
            }
            #pragma unroll
            for (int ct = 0; ct < 4; ct++){
                int r = wc + ct*16 + nL;
                bF[ct] = *(const bf16x8*)&Bs[r*64 + ((cb ^ (r & 7)) * 8)];
            }
            #pragma unroll
            for (int rt = 0; rt < 4; rt++)
                #pragma unroll
                for (int ct = 0; ct < 4; ct++)
                    acc[rt][ct] = __builtin_amdgcn_mfma_f32_16x16x32_bf16(aF[rt], bF[ct], acc[rt][ct], 0, 0, 0);
        }
    }
    if (cBase < D_){
        int hd = cBase >> 7;                    // 128-wide tile = exactly one head
        #pragma unroll
        for (int rt = 0; rt < 4; rt++){
            #pragma unroll
            for (int ct = 0; ct < 4; ct++){
                int o  = (wc + ct*16 + nL) & 127;
                int m0 = mBase + wr + rt*16 + q*4;
                int b = m0 >> 11, n0 = m0 & 2047;
                ushort4v v;
                #pragma unroll
                for (int r = 0; r < 4; r++) v[r] = (unsigned short)f2b(acc[rt][ct][r]);
                *(ushort4v*)&ht[((b*H_ + hd)*Do_ + o)*N_ + n0] = v;
            }
        }
    } else {
        #pragma unroll
        for (int rt = 0; rt < 4; rt++){
            #pragma unroll
            for (int ct = 0; ct < 4; ct++){
                int d  = cBase - D_ + wc + ct*16 + nL;
                int m0 = mBase + wr + rt*16 + q*4;
                #pragma unroll
                for (int r = 0; r < 4; r++) outg[(size_t)(m0 + r)*D_ + d] = acc[rt][ct][r];
            }
        }
    }
}

// -------- Kernel B (fallback, verified round-0): f32 A staging + pk2 --------
__global__ __launch_bounds__(256) void k_gemm_f32(const float* __restrict__ A,
                                                  const short* __restrict__ Bm,
                                                  short* __restrict__ ht,
                                                  float* outg){
    __shared__ short As[128][72];   // row stride 144B (16B-mult)
    __shared__ short Bs[128][72];
    int tid = threadIdx.x;
    int mBase = blockIdx.y * 128, cBase = blockIdx.x * 128;
    int wave = tid >> 6, lane = tid & 63, q = lane >> 4, nL = lane & 15;
    int wr = (wave >> 1) * 64, wc = (wave & 1) * 64;
    f32x4 acc[4][4] = {};
    for (int kk = 0; kk < D_; kk += 64){
        __syncthreads();
        #pragma unroll
        for (int i = 0; i < 8; i++){            // A: 128 rows x 64 k, f32 -> bf16
            int idx = tid + i*256;              // [0,2048)
            int row = idx >> 4, c4 = (idx & 15) * 4;
            float4v av = *(const float4v*)&A[(mBase+row)*D_ + kk + c4];
            int2v w; w[0] = pk2(av[0], av[1]); w[1] = pk2(av[2], av[3]);
            *(int2v*)&As[row][c4] = w;
        }
        #pragma unroll
        for (int i = 0; i < 4; i++){            // B: 128 rows x 64 k, bf16
            int idx = tid + i*256;              // [0,1024)
            int row = idx >> 3, cs = (idx & 7) * 8;
            *(int4v*)&Bs[row][cs] = *(const int4v*)&Bm[(cBase+row)*D_ + kk + cs];
        }
        __syncthreads();
        #pragma unroll
        for (int k2 = 0; k2 < 64; k2 += 32){
            bf16x8 aF[4], bF[4];
            #pragma unroll
            for (int rt = 0; rt < 4; rt++) aF[rt] = *(const bf16x8*)&As[wr + rt*16 + nL][k2 + q*8];
            #pragma unroll
            for (int ct = 0; ct < 4; ct++) bF[ct] = *(const bf16x8*)&Bs[wc + ct*16 + nL][k2 + q*8];
            #pragma unroll
            for (int rt = 0; rt < 4; rt++)
                #pragma unroll
                for (int ct = 0; ct < 4; ct++)
                    acc[rt][ct] = __builtin_amdgcn_mfma_f32_16x16x32_bf16(aF[rt], bF[ct], acc[rt][ct], 0, 0, 0);
        }
    }
    if (cBase < D_){
        int hd = cBase >> 7;
        #pragma unroll
        for (int rt = 0; rt < 4; rt++){
            #pragma unroll
            for (int ct = 0; ct < 4; ct++){
                int o  = (wc + ct*16 + nL) & 127;
                int m0 = mBase + wr + rt*16 + q*4;
                int b = m0 >> 11, n0 = m0 & 2047;
                ushort4v v;
                #pragma unroll
                for (int r = 0; r < 4; r++) v[r] = (unsigned short)f2b(acc[rt][ct][r]);
                *(ushort4v*)&ht[((b*H_ + hd)*Do_ + o)*N_ + n0] = v;
            }
        }
    } else {
        #pragma unroll
        for (int rt = 0; rt < 4; rt++){
            #pragma unroll
            for (int ct = 0; ct < 4; ct++){
                int d  = cBase - D_ + wc + ct*16 + nL;
                int m0 = mBase + wr + rt*16 + q*4;
                #pragma unroll
                for (int r = 0; r < 4; r++) outg[(size_t)(m0 + r)*D_ + d] = acc[rt][ct][r];
            }
        }
    }
}

// -------- Kernel C: attn_src/dst partials = tanh(h).w over o-range, 4-way split --------
__global__ __launch_bounds__(256) void k_stats(const short* __restrict__ ht,
                                               const float* __restrict__ wsrc,
                                               const float* __restrict__ wdst,
                                               float* __restrict__ srcP,
                                               float* __restrict__ dstP){
    int g = blockIdx.x * 256 + threadIdx.x;     // g = bh*2048 + n
    int y = blockIdx.y, o0 = y * 32;
    int bh = g >> 11, n = g & 2047;
    int hd = bh % H_;
    const short* hp = ht + bh*Do_*N_ + n + o0*N_;
    const float* ws = wsrc + hd*Do_ + o0;
    const float* wd = wdst + hd*Do_ + o0;
    float as = 0.f, ad = 0.f;
    for (int o = 0; o < 32; o++){
        float t = fast_tanh(b2f(hp[o*N_]));
        as += t * ws[o];
        ad += t * wd[o];
    }
    srcP[y*SROW + g] = as; dstP[y*SROW + g] = ad;
}

// -------- Kernel E: O = softmax(S)@h fused --------
// P = adj ? exp(leaky(src_i+dst_j)) : 0 = adj ? max(e1_i*E1_j, e2_i*E2_j) : 0.
// E1/E2 staged in LDS (no exp in hot loop). l = P@ones via extra MFMA.
// XCD-chunked remap: 3 (b,hd) ht-slabs per XCD -> slab fetched into local L2 once.
struct StageS {
    float E1[2048];             // 8KB
    float E2[2048];             // 8KB
    unsigned pkw[64*65];        // 16.6KB, 65-u32 row stride
};
struct RedS { float red[2][64][37]; };  // 18.9KB; stride 37 words -> 2-way max
union LdsU { StageS s; RedS r; };
__global__ __launch_bounds__(256) void k_pv(const unsigned char* __restrict__ pkG,
                                            const float* __restrict__ srcP,
                                            const float* __restrict__ dstP,
                                            const short* __restrict__ ht,
                                            const float* __restrict__ feat_in,
                                            const float* __restrict__ bias,
                                            const float* __restrict__ Hb,
                                            float* outg){
    __shared__ LdsU U;
    int lid = blockIdx.x;
    int nid = (lid & 7)*96 + (lid >> 3);        // bijective chunked XCD remap
    int itile = nid & 31;
    int hd = (nid >> 5) % 6, b = nid / 192;
    int tid = threadIdx.x, wave = tid >> 6, lane = tid & 63, q = lane >> 4, nL = lane & 15;
    int rh = wave >> 1, kh = wave & 1;
    int r0 = itile * 64;
    int bh = b*H_ + hd;
    // ---- stage E1/E2 (from 4-way dst partials) and packed adj (64 rows) ----
    {
        const float4v* g0 = (const float4v*)(dstP + bh*N_);
        const float4v* g1 = (const float4v*)(dstP + SROW + bh*N_);
        const float4v* g2 = (const float4v*)(dstP + 2*SROW + bh*N_);
        const float4v* g3 = (const float4v*)(dstP + 3*SROW + bh*N_);
        #pragma unroll
        for (int h = 0; h < 2; h++){
            int c4 = tid*2 + h;
            float4v d = g0[c4] + g1[c4] + g2[c4] + g3[c4];
            #pragma unroll
            for (int t = 0; t < 4; t++){
                U.s.E1[c4*4 + t] = __expf(d[t]);
                U.s.E2[c4*4 + t] = __expf(0.2f * d[t]);
            }
        }
        const unsigned* pg = (const unsigned*)(pkG + (size_t)(b*N_ + r0) * (N_/8));
        #pragma unroll
        for (int k = 0; k < 16; k++){
            int idx = tid + k*256;              // [0,4096)
            U.s.pkw[(idx >> 6)*65 + (idx & 63)] = pg[idx];
        }
    }
    __syncthreads();
    int rowL0 = rh*32 + nL, rowL1 = rowL0 + 16;
    int gi0 = bh*N_ + r0 + rowL0, gi1 = bh*N_ + r0 + rowL1;
    float s0 = srcP[gi0] + srcP[SROW+gi0] + srcP[2*SROW+gi0] + srcP[3*SROW+gi0];
    float s1 = srcP[gi1] + srcP[SROW+gi1] + srcP[2*SROW+gi1] + srcP[3*SROW+gi1];
    float e1r0 = __expf(s0), e2r0 = __expf(0.2f*s0);
    float e1r1 = __expf(s1), e2r1 = __expf(0.2f*s1);
    bf16x8 vone;
    #pragma unroll
    for (int t = 0; t < 8; t++) vone[t] = (short)0x3F80;   // bf16 1.0
    const short* hp = ht + bh*Do_*N_;
    f32x4 acc[2][8] = {};
    f32x4 accl0 = {}, accl1 = {};
    int base0 = rowL0*65, base1 = rowL1*65;
    int jEnd = kh*1024 + 1024;
    for (int j0 = kh*1024; j0 < jEnd; j0 += 32){
        unsigned by0 = (U.s.pkw[base0 + (j0 >> 5)] >> (q*8)) & 0xFF;
        unsigned by1 = (U.s.pkw[base1 + (j0 >> 5)] >> (q*8)) & 0xFF;
        int kb = j0 + q*8;
        float4v E1a = *(const float4v*)&U.s.E1[kb];
        float4v E1b = *(const float4v*)&U.s.E1[kb + 4];
        float4v E2a = *(const float4v*)&U.s.E2[kb];
        float4v E2b = *(const float4v*)&U.s.E2[kb + 4];
        float p0[8], p1[8];
        #pragma unroll
        for (int t = 0; t < 8; t++){
            float E1t = t < 4 ? E1a[t] : E1b[t-4];
            float E2t = t < 4 ? E2a[t] : E2b[t-4];
            float a0 = fmaxf(e1r0*E1t, e2r0*E2t);
            float a1 = fmaxf(e1r1*E1t, e2r1*E2t);
            p0[t] = ((by0 >> t) & 1u) ? a0 : 0.0f;
            p1[t] = ((by1 >> t) & 1u) ? a1 : 0.0f;
        }
        int4v pi0, pi1;
        #pragma unroll
        for (int tp = 0; tp < 4; tp++){
            pi0[tp] = pk2(p0[2*tp], p0[2*tp+1]);
            pi1[tp] = pk2(p1[2*tp], p1[2*tp+1]);
        }
        bf16x8 pf0 = __builtin_bit_cast(bf16x8, pi0);
        bf16x8 pf1 = __builtin_bit_cast(bf16x8, pi1);
        #pragma unroll
        for (int ct = 0; ct < 8; ct++){
            bf16x8 bF = *(const bf16x8*)&hp[(ct*16 + nL)*N_ + kb];
            acc[0][ct] = __builtin_amdgcn_mfma_f32_16x16x32_bf16(pf0, bF, acc[0][ct], 0, 0, 0);
            acc[1][ct] = __builtin_amdgcn_mfma_f32_16x16x32_bf16(pf1, bF, acc[1][ct], 0, 0, 0);
        }
        accl0 = __builtin_amdgcn_mfma_f32_16x16x32_bf16(pf0, vone, accl0, 0, 0, 0);
        accl1 = __builtin_amdgcn_mfma_f32_16x16x32_bf16(pf1, vone, accl1, 0, 0, 0);
    }
    // ---- 2-phase cross-kh reduction (staging LDS reused) ----
    __syncthreads();
    if (kh == 1){
        #pragma unroll
        for (int ct = 0; ct < 8; ct++)
            #pragma unroll
            for (int r = 0; r < 4; r++) U.r.red[rh][lane][ct*4 + r] = acc[0][ct][r];
        #pragma unroll
        for (int r = 0; r < 4; r++) U.r.red[rh][lane][32 + r] = accl0[r];
    }
    __syncthreads();
    if (kh == 0){
        #pragma unroll
        for (int ct = 0; ct < 8; ct++)
            #pragma unroll
            for (int r = 0; r < 4; r++) acc[0][ct][r] += U.r.red[rh][lane][ct*4 + r];
        #pragma unroll
        for (int r = 0; r < 4; r++) accl0[r] += U.r.red[rh][lane][32 + r];
    }
    __syncthreads();
    if (kh == 0){
        #pragma unroll
        for (int ct = 0; ct < 8; ct++)
            #pragma unroll
            for (int r = 0; r < 4; r++) U.r.red[rh][lane][ct*4 + r] = acc[1][ct][r];
        #pragma unroll
        for (int r = 0; r < 4; r++) U.r.red[rh][lane][32 + r] = accl1[r];
    }
    __syncthreads();
    if (kh == 1){
        #pragma unroll
        for (int ct = 0; ct < 8; ct++)
            #pragma unroll
            for (int r = 0; r < 4; r++) acc[1][ct][r] += U.r.red[rh][lane][ct*4 + r];
        #pragma unroll
        for (int r = 0; r < 4; r++) accl1[r] += U.r.red[rh][lane][32 + r];
    }
    // ---- epilogue: wave kh handles frag kh (16 rows) ----
    {
        int f = kh;
        f32x4 accl = f ? accl1 : accl0;
        #pragma unroll
        for (int r = 0; r < 4; r++){
            int i = r0 + rh*32 + f*16 + q*4 + r;
            float invl = 1.0f / accl[r];
            size_t base = (size_t)(b*N_ + i)*D_ + hd*Do_;
            #pragma unroll
            for (int ct = 0; ct < 8; ct++){
                int o = ct*16 + nL;
                float v = acc[f][ct][r]*invl + bias[o];
                float e = v > 0.f ? v : __expf(v) - 1.0f;
                float gl = outg[base + o] + Hb[hd*Do_ + o];
                float g = 1.0f / (1.0f + __expf(-gl));
                float fi = feat_in[base + o];
                outg[base + o] = g*e + (1.0f - g)*fi;
            }
        }
    }
}

extern "C" void kernel_launch(void* const* d_in, const int* in_sizes, int n_in,
                              void* d_out, int out_size, void* d_ws, size_t ws_size,
                              hipStream_t stream){
    const float* feat = (const float*)d_in[0];
    const int*   adj  = (const int*)  d_in[1];
    const float* W    = (const float*)d_in[2];
    const float* bias = (const float*)d_in[3];
    const float* wsrc = (const float*)d_in[4];
    const float* wdst = (const float*)d_in[5];
    const float* Hw   = (const float*)d_in[6];
    const float* Hb   = (const float*)d_in[7];
    float* out = (float*)d_out;
    char* ws = (char*)d_ws;
    // Workspace base layout (18,612,224 bytes, as the verified session):
    //   bmat   [0, 2,359,296)
    //   ht     [2,359,296, 14,942,208)
    //   srcP   [14,942,208, 15,728,640)   4 x 49152 f32 partials
    //   dstP   [15,728,640, 16,515,072)
    //   pk     [16,515,072, 18,612,224)
    // Optional (only if ws_size permits):
    //   featbf [18,612,224, 31,195,136)   8192x768 bf16
    short* bmat = (short*)(ws);
    short* ht   = (short*)(ws + 2359296);
    float* srcP = (float*)(ws + 14942208);
    float* dstP = (float*)(ws + 15728640);
    unsigned char* pk = (unsigned char*)(ws + 16515072);
    short* featbf = (short*)(ws + 18612224);
    bool big = ws_size >= (size_t)31195136;

    int prepGrid = C2_ + 8192 + (big ? 3072 : 0);
    hipLaunchKernelGGL(k_prep_pack, dim3(prepGrid), dim3(256), 0, stream,
                       W, Hw, feat, adj, bmat, featbf, pk);
    if (big)
        hipLaunchKernelGGL(k_gemm_bf,  dim3(768),    dim3(256), 0, stream, featbf, bmat, ht, out);
    else
        hipLaunchKernelGGL(k_gemm_f32, dim3(12, 64), dim3(256), 0, stream, feat, bmat, ht, out);
    hipLaunchKernelGGL(k_stats, dim3(192, 4), dim3(256), 0, stream, ht, wsrc, wdst, srcP, dstP);
    hipLaunchKernelGGL(k_pv,    dim3(768),    dim3(256), 0, stream, pk, srcP, dstP,
                       ht, feat, bias, Hb, out);
}

// Round 3
// 259.595 us; speedup vs baseline: 1.2235x; 1.1681x over previous
//
#include <hip/hip_runtime.h>
#include <hip/hip_bf16.h>

#define B_ 4
#define N_ 2048
#define D_ 768
#define H_ 6
#define Do_ 128
#define M_ (B_*N_)      // 8192
#define C2_ (2*D_)      // 1536
#define SROW 49152      // B_*H_*N_

typedef __attribute__((ext_vector_type(8))) short bf16x8;
typedef __attribute__((ext_vector_type(4))) float f32x4;
typedef __attribute__((ext_vector_type(4))) int int4v;
typedef __attribute__((ext_vector_type(2))) int int2v;
typedef __attribute__((ext_vector_type(4))) float float4v;
typedef __attribute__((ext_vector_type(4))) unsigned short ushort4v;

__device__ __forceinline__ float b2f(short s){
    unsigned u = ((unsigned)(unsigned short)s) << 16;
    return __builtin_bit_cast(float, u);
}
__device__ __forceinline__ short f2b(float f){
    unsigned u = __builtin_bit_cast(unsigned, f);
    unsigned r = (u + 0x7fffu + ((u >> 16) & 1u)) >> 16;
    return (short)r;
}
// pack two f32 -> two bf16 (round-half-up) in one v_perm
__device__ __forceinline__ int pk2(float a, float b){
    unsigned ua = __builtin_bit_cast(unsigned, a) + 0x8000u;
    unsigned ub = __builtin_bit_cast(unsigned, b) + 0x8000u;
    return (int)__builtin_amdgcn_perm(ub, ua, 0x07060302u); // lo16=hi(ua), hi16=hi(ub)
}
__device__ __forceinline__ float fast_tanh(float x){
    float a = fabsf(x);
    float e = __expf(-2.0f * a);
    float t = (1.0f - e) / (1.0f + e);
    return copysignf(t, x);
}
// async global->LDS, 16B per lane. LDS dest = wave-uniform base + lane*16.
__device__ __forceinline__ void gload_lds16(const void* g, void* l){
    __builtin_amdgcn_global_load_lds((const __attribute__((address_space(1))) unsigned int*)g,
                                     (__attribute__((address_space(3))) unsigned int*)l,
                                     16, 0, 0);
}

// ht tiled layout: ht[bh][jt=n>>5][o(128)][jl=n&31], 64B per (o,jt) row.
// PV B-frag load (lane o=ct*16+nL, col q*8) = base + o*64B + q*16B -> one 1KB
// fully-coalesced transaction per instruction (was a 16-segment 4KB-stride gather).
#define HT_IDX(bh, n, o) ((((size_t)((bh)*64 + ((n) >> 5))*128 + (o))*32) + ((n) & 31))

// -------- Kernel A: pack B^T matrix (f32->bf16) + bit-pack adj (+ feat f32->bf16 if room) --------
__global__ __launch_bounds__(256) void k_prep_pack(const float* __restrict__ W,
                                                   const float* __restrict__ Hw,
                                                   const float* __restrict__ feat,
                                                   const int* __restrict__ adj,
                                                   short* __restrict__ bmat,
                                                   short* __restrict__ featbf,
                                                   unsigned char* __restrict__ pk){
    int bid = blockIdx.x, t = threadIdx.x;
    if (bid < C2_){
        int c = bid;
        if (c < D_){
            int hd = c >> 7, o = c & 127;
            const float* wp = W + hd*D_*Do_ + o;
            for (int k = t; k < D_; k += 256) bmat[c*D_ + k] = f2b(wp[k*Do_]);
        } else {
            int d = c - D_;
            const float* hp = Hw + d*D_;
            for (int k = t; k < D_; k += 256) bmat[c*D_ + k] = f2b(hp[k]);
        }
    } else if (bid < C2_ + 8192){
        int g = (bid - C2_)*256 + t;            // one byte per thread
        const int* ap = adj + (size_t)g*8;
        int4v a0 = *(const int4v*)ap;
        int4v a1 = *(const int4v*)(ap + 4);
        unsigned by = 0;
        #pragma unroll
        for (int i = 0; i < 4; i++){
            by |= (a0[i] ? 1u : 0u) << i;
            by |= (a1[i] ? 1u : 0u) << (i + 4);
        }
        pk[g] = (unsigned char)by;
    } else {
        int g = (bid - C2_ - 8192)*2048 + t*8;  // 8 f32 -> 8 bf16 per thread
        float4v a0 = *(const float4v*)&feat[g];
        float4v a1 = *(const float4v*)&feat[g + 4];
        int4v w;
        w[0] = pk2(a0[0], a0[1]); w[1] = pk2(a0[2], a0[3]);
        w[2] = pk2(a1[0], a1[1]); w[3] = pk2(a1[2], a1[3]);
        *(int4v*)&featbf[g] = w;
    }
}

// -------- Kernel B (primary): C[8192,1536] = Abf[8192,768] @ Bm^T, 128x128 tile --------
__global__ __launch_bounds__(256) void k_gemm_bf(const short* __restrict__ Abf,
                                                 const short* __restrict__ Bm,
                                                 short* __restrict__ ht,
                                                 float* outg){
    __shared__ short As[128*64];    // 16KB, row = 64 bf16 = 128B, swizzled storage
    __shared__ short Bs[128*64];
    int lid = blockIdx.x;
    int nid = (lid & 7)*96 + (lid >> 3);        // bijective: 768 % 8 == 0
    int bx = nid % 12, by = nid / 12;           // col-tile (12), row-tile (64)
    int mBase = by * 128, cBase = bx * 128;
    int tid = threadIdx.x, wave = tid >> 6, lane = tid & 63, q = lane >> 4, nL = lane & 15;
    int wr = (wave >> 1) * 64, wc = (wave & 1) * 64;
    int srow = tid >> 3;                        // 0..31
    int sc16 = (tid & 7) ^ (srow & 7);
    const short* aSrc = Abf + (size_t)(mBase + srow)*D_ + sc16*8;
    const short* bSrc = Bm  + (size_t)(cBase + srow)*D_ + sc16*8;
    short* aDst = &As[wave*512];                // + i*2048 shorts (4KB/issue)
    short* bDst = &Bs[wave*512];
    f32x4 acc[4][4] = {};
    for (int kk = 0; kk < D_; kk += 64){
        __syncthreads();
        #pragma unroll
        for (int i = 0; i < 4; i++)
            gload_lds16(aSrc + (size_t)i*32*D_ + kk, aDst + i*2048);
        #pragma unroll
        for (int i = 0; i < 4; i++)
            gload_lds16(bSrc + (size_t)i*32*D_ + kk, bDst + i*2048);
        __syncthreads();                        // compiler drains vmcnt before barrier
        #pragma unroll
        for (int k2 = 0; k2 < 64; k2 += 32){
            bf16x8 aF[4], bF[4];
            int cb = (k2 >> 3) + q;             // pre-swizzle col16 (0..7)
            #pragma unroll
            for (int rt = 0; rt < 4; rt++){
                int r = wr + rt*16 + nL;
                aF[rt] = *(const bf16x8*)&As[r*64 + ((cb ^ (r & 7)) * 8)];
            }
            #pragma unroll
            for (int ct = 0; ct < 4; ct++){
                int r = wc + ct*16 + nL;
                bF[ct] = *(const bf16x8*)&Bs[r*64 + ((cb ^ (r & 7)) * 8)];
            }
            #pragma unroll
            for (int rt = 0; rt < 4; rt++)
                #pragma unroll
                for (int ct = 0; ct < 4; ct++)
                    acc[rt][ct] = __builtin_amdgcn_mfma_f32_16x16x32_bf16(aF[rt], bF[ct], acc[rt][ct], 0, 0, 0);
        }
    }
    if (cBase < D_){
        int hd = cBase >> 7;                    // 128-wide tile = exactly one head
        #pragma unroll
        for (int rt = 0; rt < 4; rt++){
            #pragma unroll
            for (int ct = 0; ct < 4; ct++){
                int o  = (wc + ct*16 + nL) & 127;
                int m0 = mBase + wr + rt*16 + q*4;
                int b = m0 >> 11, n0 = m0 & 2047;
                int bh = b*H_ + hd;
                ushort4v v;
                #pragma unroll
                for (int r = 0; r < 4; r++) v[r] = (unsigned short)f2b(acc[rt][ct][r]);
                *(ushort4v*)&ht[HT_IDX(bh, n0, o)] = v;   // n0%4==0, stays in one jl-block
            }
        }
    } else {
        #pragma unroll
        for (int rt = 0; rt < 4; rt++){
            #pragma unroll
            for (int ct = 0; ct < 4; ct++){
                int d  = cBase - D_ + wc + ct*16 + nL;
                int m0 = mBase + wr + rt*16 + q*4;
                #pragma unroll
                for (int r = 0; r < 4; r++) outg[(size_t)(m0 + r)*D_ + d] = acc[rt][ct][r];
            }
        }
    }
}

// -------- Kernel B (fallback): f32 A staging + pk2 --------
__global__ __launch_bounds__(256) void k_gemm_f32(const float* __restrict__ A,
                                                  const short* __restrict__ Bm,
                                                  short* __restrict__ ht,
                                                  float* outg){
    __shared__ short As[128][72];   // row stride 144B (16B-mult)
    __shared__ short Bs[128][72];
    int tid = threadIdx.x;
    int mBase = blockIdx.y * 128, cBase = blockIdx.x * 128;
    int wave = tid >> 6, lane = tid & 63, q = lane >> 4, nL = lane & 15;
    int wr = (wave >> 1) * 64, wc = (wave & 1) * 64;
    f32x4 acc[4][4] = {};
    for (int kk = 0; kk < D_; kk += 64){
        __syncthreads();
        #pragma unroll
        for (int i = 0; i < 8; i++){            // A: 128 rows x 64 k, f32 -> bf16
            int idx = tid + i*256;              // [0,2048)
            int row = idx >> 4, c4 = (idx & 15) * 4;
            float4v av = *(const float4v*)&A[(mBase+row)*D_ + kk + c4];
            int2v w; w[0] = pk2(av[0], av[1]); w[1] = pk2(av[2], av[3]);
            *(int2v*)&As[row][c4] = w;
        }
        #pragma unroll
        for (int i = 0; i < 4; i++){            // B: 128 rows x 64 k, bf16
            int idx = tid + i*256;              // [0,1024)
            int row = idx >> 3, cs = (idx & 7) * 8;
            *(int4v*)&Bs[row][cs] = *(const int4v*)&Bm[(cBase+row)*D_ + kk + cs];
        }
        __syncthreads();
        #pragma unroll
        for (int k2 = 0; k2 < 64; k2 += 32){
            bf16x8 aF[4], bF[4];
            #pragma unroll
            for (int rt = 0; rt < 4; rt++) aF[rt] = *(const bf16x8*)&As[wr + rt*16 + nL][k2 + q*8];
            #pragma unroll
            for (int ct = 0; ct < 4; ct++) bF[ct] = *(const bf16x8*)&Bs[wc + ct*16 + nL][k2 + q*8];
            #pragma unroll
            for (int rt = 0; rt < 4; rt++)
                #pragma unroll
                for (int ct = 0; ct < 4; ct++)
                    acc[rt][ct] = __builtin_amdgcn_mfma_f32_16x16x32_bf16(aF[rt], bF[ct], acc[rt][ct], 0, 0, 0);
        }
    }
    if (cBase < D_){
        int hd = cBase >> 7;
        #pragma unroll
        for (int rt = 0; rt < 4; rt++){
            #pragma unroll
            for (int ct = 0; ct < 4; ct++){
                int o  = (wc + ct*16 + nL) & 127;
                int m0 = mBase + wr + rt*16 + q*4;
                int b = m0 >> 11, n0 = m0 & 2047;
                int bh = b*H_ + hd;
                ushort4v v;
                #pragma unroll
                for (int r = 0; r < 4; r++) v[r] = (unsigned short)f2b(acc[rt][ct][r]);
                *(ushort4v*)&ht[HT_IDX(bh, n0, o)] = v;
            }
        }
    } else {
        #pragma unroll
        for (int rt = 0; rt < 4; rt++){
            #pragma unroll
            for (int ct = 0; ct < 4; ct++){
                int d  = cBase - D_ + wc + ct*16 + nL;
                int m0 = mBase + wr + rt*16 + q*4;
                #pragma unroll
                for (int r = 0; r < 4; r++) outg[(size_t)(m0 + r)*D_ + d] = acc[rt][ct][r];
            }
        }
    }
}

// -------- Kernel C: attn_src/dst partials = tanh(h).w over o-range, 4-way split --------
__global__ __launch_bounds__(256) void k_stats(const short* __restrict__ ht,
                                               const float* __restrict__ wsrc,
                                               const float* __restrict__ wdst,
                                               float* __restrict__ srcP,
                                               float* __restrict__ dstP){
    int g = blockIdx.x * 256 + threadIdx.x;     // g = bh*2048 + n
    int y = blockIdx.y, o0 = y * 32;
    int bh = g >> 11, n = g & 2047;
    int hd = bh % H_;
    const short* hp = ht + HT_IDX(bh, n, o0);   // +32 shorts per o
    const float* ws = wsrc + hd*Do_ + o0;
    const float* wd = wdst + hd*Do_ + o0;
    float as = 0.f, ad = 0.f;
    for (int o = 0; o < 32; o++){
        float t = fast_tanh(b2f(hp[o*32]));
        as += t * ws[o];
        ad += t * wd[o];
    }
    srcP[y*SROW + g] = as; dstP[y*SROW + g] = ad;
}

// -------- Kernel E: O = softmax(S)@h fused --------
struct StageS {
    float E1[2048];             // 8KB
    float E2[2048];             // 8KB
    unsigned pkw[64*65];        // 16.6KB, 65-u32 row stride
};
struct RedS { float red[2][64][37]; };  // 18.9KB; stride 37 words -> 2-way max
union LdsU { StageS s; RedS r; };
__global__ __launch_bounds__(256) void k_pv(const unsigned char* __restrict__ pkG,
                                            const float* __restrict__ srcP,
                                            const float* __restrict__ dstP,
                                            const short* __restrict__ ht,
                                            const float* __restrict__ feat_in,
                                            const float* __restrict__ bias,
                                            const float* __restrict__ Hb,
                                            float* outg){
    __shared__ LdsU U;
    int lid = blockIdx.x;
    int nid = (lid & 7)*96 + (lid >> 3);        // bijective chunked XCD remap
    int itile = nid & 31;
    int hd = (nid >> 5) % 6, b = nid / 192;
    int tid = threadIdx.x, wave = tid >> 6, lane = tid & 63, q = lane >> 4, nL = lane & 15;
    int rh = wave >> 1, kh = wave & 1;
    int r0 = itile * 64;
    int bh = b*H_ + hd;
    // ---- stage E1/E2 (from 4-way dst partials) and packed adj (64 rows) ----
    {
        const float4v* g0 = (const float4v*)(dstP + bh*N_);
        const float4v* g1 = (const float4v*)(dstP + SROW + bh*N_);
        const float4v* g2 = (const float4v*)(dstP + 2*SROW + bh*N_);
        const float4v* g3 = (const float4v*)(dstP + 3*SROW + bh*N_);
        #pragma unroll
        for (int h = 0; h < 2; h++){
            int c4 = tid*2 + h;
            float4v d = g0[c4] + g1[c4] + g2[c4] + g3[c4];
            #pragma unroll
            for (int t = 0; t < 4; t++){
                U.s.E1[c4*4 + t] = __expf(d[t]);
                U.s.E2[c4*4 + t] = __expf(0.2f * d[t]);
            }
        }
        const unsigned* pg = (const unsigned*)(pkG + (size_t)(b*N_ + r0) * (N_/8));
        #pragma unroll
        for (int k = 0; k < 16; k++){
            int idx = tid + k*256;              // [0,4096)
            U.s.pkw[(idx >> 6)*65 + (idx & 63)] = pg[idx];
        }
    }
    __syncthreads();
    int rowL0 = rh*32 + nL, rowL1 = rowL0 + 16;
    int gi0 = bh*N_ + r0 + rowL0, gi1 = bh*N_ + r0 + rowL1;
    float s0 = srcP[gi0] + srcP[SROW+gi0] + srcP[2*SROW+gi0] + srcP[3*SROW+gi0];
    float s1 = srcP[gi1] + srcP[SROW+gi1] + srcP[2*SROW+gi1] + srcP[3*SROW+gi1];
    float e1r0 = __expf(s0), e2r0 = __expf(0.2f*s0);
    float e1r1 = __expf(s1), e2r1 = __expf(0.2f*s1);
    bf16x8 vone;
    #pragma unroll
    for (int t = 0; t < 8; t++) vone[t] = (short)0x3F80;   // bf16 1.0
    const short* hp = ht + (size_t)bh*262144;   // bh slab, tiled [jt][o][jl]
    f32x4 acc[2][8] = {};
    f32x4 accl0 = {}, accl1 = {};
    int base0 = rowL0*65, base1 = rowL1*65;
    int jEnd = kh*1024 + 1024;
    for (int j0 = kh*1024; j0 < jEnd; j0 += 32){
        unsigned by0 = (U.s.pkw[base0 + (j0 >> 5)] >> (q*8)) & 0xFF;
        unsigned by1 = (U.s.pkw[base1 + (j0 >> 5)] >> (q*8)) & 0xFF;
        int kb = j0 + q*8;
        const short* hj = hp + (size_t)(j0 >> 5)*4096 + q*8;   // [jt][o][jl] tile
        float4v E1a = *(const float4v*)&U.s.E1[kb];
        float4v E1b = *(const float4v*)&U.s.E1[kb + 4];
        float4v E2a = *(const float4v*)&U.s.E2[kb];
        float4v E2b = *(const float4v*)&U.s.E2[kb + 4];
        float p0[8], p1[8];
        #pragma unroll
        for (int t = 0; t < 8; t++){
            float E1t = t < 4 ? E1a[t] : E1b[t-4];
            float E2t = t < 4 ? E2a[t] : E2b[t-4];
            float a0 = fmaxf(e1r0*E1t, e2r0*E2t);
            float a1 = fmaxf(e1r1*E1t, e2r1*E2t);
            p0[t] = ((by0 >> t) & 1u) ? a0 : 0.0f;
            p1[t] = ((by1 >> t) & 1u) ? a1 : 0.0f;
        }
        int4v pi0, pi1;
        #pragma unroll
        for (int tp = 0; tp < 4; tp++){
            pi0[tp] = pk2(p0[2*tp], p0[2*tp+1]);
            pi1[tp] = pk2(p1[2*tp], p1[2*tp+1]);
        }
        bf16x8 pf0 = __builtin_bit_cast(bf16x8, pi0);
        bf16x8 pf1 = __builtin_bit_cast(bf16x8, pi1);
        #pragma unroll
        for (int ct = 0; ct < 8; ct++){
            bf16x8 bF = *(const bf16x8*)&hj[(ct*16 + nL)*32];  // coalesced 1KB/instr
            acc[0][ct] = __builtin_amdgcn_mfma_f32_16x16x32_bf16(pf0, bF, acc[0][ct], 0, 0, 0);
            acc[1][ct] = __builtin_amdgcn_mfma_f32_16x16x32_bf16(pf1, bF, acc[1][ct], 0, 0, 0);
        }
        accl0 = __builtin_amdgcn_mfma_f32_16x16x32_bf16(pf0, vone, accl0, 0, 0, 0);
        accl1 = __builtin_amdgcn_mfma_f32_16x16x32_bf16(pf1, vone, accl1, 0, 0, 0);
    }
    // ---- 2-phase cross-kh reduction (staging LDS reused) ----
    __syncthreads();
    if (kh == 1){
        #pragma unroll
        for (int ct = 0; ct < 8; ct++)
            #pragma unroll
            for (int r = 0; r < 4; r++) U.r.red[rh][lane][ct*4 + r] = acc[0][ct][r];
        #pragma unroll
        for (int r = 0; r < 4; r++) U.r.red[rh][lane][32 + r] = accl0[r];
    }
    __syncthreads();
    if (kh == 0){
        #pragma unroll
        for (int ct = 0; ct < 8; ct++)
            #pragma unroll
            for (int r = 0; r < 4; r++) acc[0][ct][r] += U.r.red[rh][lane][ct*4 + r];
        #pragma unroll
        for (int r = 0; r < 4; r++) accl0[r] += U.r.red[rh][lane][32 + r];
    }
    __syncthreads();
    if (kh == 0){
        #pragma unroll
        for (int ct = 0; ct < 8; ct++)
            #pragma unroll
            for (int r = 0; r < 4; r++) U.r.red[rh][lane][ct*4 + r] = acc[1][ct][r];
        #pragma unroll
        for (int r = 0; r < 4; r++) U.r.red[rh][lane][32 + r] = accl1[r];
    }
    __syncthreads();
    if (kh == 1){
        #pragma unroll
        for (int ct = 0; ct < 8; ct++)
            #pragma unroll
            for (int r = 0; r < 4; r++) acc[1][ct][r] += U.r.red[rh][lane][ct*4 + r];
        #pragma unroll
        for (int r = 0; r < 4; r++) accl1[r] += U.r.red[rh][lane][32 + r];
    }
    // ---- epilogue: wave kh handles frag kh (16 rows) ----
    {
        int f = kh;
        f32x4 accl = f ? accl1 : accl0;
        #pragma unroll
        for (int r = 0; r < 4; r++){
            int i = r0 + rh*32 + f*16 + q*4 + r;
            float invl = 1.0f / accl[r];
            size_t base = (size_t)(b*N_ + i)*D_ + hd*Do_;
            #pragma unroll
            for (int ct = 0; ct < 8; ct++){
                int o = ct*16 + nL;
                float v = acc[f][ct][r]*invl + bias[o];
                float e = v > 0.f ? v : __expf(v) - 1.0f;
                float gl = outg[base + o] + Hb[hd*Do_ + o];
                float g = 1.0f / (1.0f + __expf(-gl));
                float fi = feat_in[base + o];
                outg[base + o] = g*e + (1.0f - g)*fi;
            }
        }
    }
}

extern "C" void kernel_launch(void* const* d_in, const int* in_sizes, int n_in,
                              void* d_out, int out_size, void* d_ws, size_t ws_size,
                              hipStream_t stream){
    const float* feat = (const float*)d_in[0];
    const int*   adj  = (const int*)  d_in[1];
    const float* W    = (const float*)d_in[2];
    const float* bias = (const float*)d_in[3];
    const float* wsrc = (const float*)d_in[4];
    const float* wdst = (const float*)d_in[5];
    const float* Hw   = (const float*)d_in[6];
    const float* Hb   = (const float*)d_in[7];
    float* out = (float*)d_out;
    char* ws = (char*)d_ws;
    // Workspace base layout (18,612,224 bytes):
    //   bmat   [0, 2,359,296)
    //   ht     [2,359,296, 14,942,208)    tiled [bh][jt][o][jl]
    //   srcP   [14,942,208, 15,728,640)   4 x 49152 f32 partials
    //   dstP   [15,728,640, 16,515,072)
    //   pk     [16,515,072, 18,612,224)
    // Optional (only if ws_size permits):
    //   featbf [18,612,224, 31,195,136)   8192x768 bf16
    short* bmat = (short*)(ws);
    short* ht   = (short*)(ws + 2359296);
    float* srcP = (float*)(ws + 14942208);
    float* dstP = (float*)(ws + 15728640);
    unsigned char* pk = (unsigned char*)(ws + 16515072);
    short* featbf = (short*)(ws + 18612224);
    bool big = ws_size >= (size_t)31195136;

    int prepGrid = C2_ + 8192 + (big ? 3072 : 0);
    hipLaunchKernelGGL(k_prep_pack, dim3(prepGrid), dim3(256), 0, stream,
                       W, Hw, feat, adj, bmat, featbf, pk);
    if (big)
        hipLaunchKernelGGL(k_gemm_bf,  dim3(768),    dim3(256), 0, stream, featbf, bmat, ht, out);
    else
        hipLaunchKernelGGL(k_gemm_f32, dim3(12, 64), dim3(256), 0, stream, feat, bmat, ht, out);
    hipLaunchKernelGGL(k_stats, dim3(192, 4), dim3(256), 0, stream, ht, wsrc, wdst, srcP, dstP);
    hipLaunchKernelGGL(k_pv,    dim3(768),    dim3(256), 0, stream, pk, srcP, dstP,
                       ht, feat, bias, Hb, out);
}